// Round 11
// baseline (237.069 us; speedup 1.0000x reference)
//
#include <hip/hip_runtime.h>
#include <math.h>

#define B_ 64
#define IC 2048
#define OC 32
#define OD 16
#define ID 8

#define GLOAD_LDS16(gp, lp)                                                       \
  __builtin_amdgcn_global_load_lds((const __attribute__((address_space(1))) void*)(gp), \
                                   (__attribute__((address_space(3))) void*)(lp), \
                                   16, 0, 0)

__device__ __forceinline__ float dot8(const float4 w0, const float4 w1,
                                      const float4 xa, const float4 xb) {
  return w0.x*xa.x + w0.y*xa.y + w0.z*xa.z + w0.w*xa.w
       + w1.x*xb.x + w1.y*xb.y + w1.z*xb.z + w1.w*xb.w;
}

// ---------------------------------------------------------------------------
// Fused routing pass (b_k = u.(v1+...+vk) algebra; unnormalized p=exp(u.vs),
// Z applied in reduceSquash).
//
// Geometry (R9, kept): grid = NCH (one block per i-chunk, 1 block/CU at
// NCH=256), block = 512 threads = 8 waves. Wave wv owns b in [wv*8,wv*8+8).
// Lane: op=lane>>2, dq=lane&3; thread owns o in {op, op+16} and d in
// [dq*4, dq*4+4). Per wave-iter: 16 W ds_read_b128 (= W[i] exactly once per
// wave, the LDS-issue minimum for this dataflow) + 16 x broadcast reads for
// 1024 wave-FMAs.
//
// R11 fix: amdgpu_waves_per_eu(2,2). R9/R10 showed the backend pins the VGPR
// budget at 128 for this 512-thread/48KB-LDS shape (4 waves/EU occupancy
// heuristic) REGARDLESS of __launch_bounds__, spilling the ~230-live tile
// (FETCH 100MB, 80us). Requesting exactly 2 waves/EU lifts the budget to
// 512-reg-pool/2 = 256 VGPR -> zero spill, 1 block/CU.
//
// W[i] (16KB) double-buffered via global_load_lds, source XOR-swizzled
// (involution p -> (p&~7)|((p&7)^((p>>3)&7))) so each thread's 8-f4 read
// per o2 spreads across all 32 banks (read index r ^ (lane&7)).
// x window [8 i][64 b][8 m] (16KB) staged once per 8-i subwindow.
// All blocks read disjoint W/x slices: pure streaming.
// ---------------------------------------------------------------------------
template<bool WEIGHTED, int NCH>
__global__ __launch_bounds__(512)
__attribute__((amdgpu_waves_per_eu(2, 2)))
void fusedK(
    const float* __restrict__ x, const float* __restrict__ W,
    const float* __restrict__ vs, float* __restrict__ part,
    float* __restrict__ zpart)
{
  constexpr int CI  = IC / NCH;
  constexpr int NSW = CI / 8;
  const int t    = threadIdx.x;
  const int ch   = blockIdx.x;
  const int lane = t & 63;
  const int wv   = t >> 6;
  const int op   = lane >> 2;
  const int dq   = lane & 3;
  const int rot  = lane & 7;
  const int i0   = ch * CI;
  const int b0   = wv * 8;             // wave's first b

  __shared__ float Wbuf[2][4096];      // 2 x 16 KB
  __shared__ float xall[1024 * 4];     // [8 i][64 b][8 m] = 16 KB

  const float4* Wg = (const float4*)W;
  const float4* xg = (const float4*)x;

  float4 acc[2][8];
  float  zacc[2][8];
  float4 vreg[2][8];
#pragma unroll
  for (int o2 = 0; o2 < 2; ++o2)
#pragma unroll
    for (int bb = 0; bb < 8; ++bb) {
      acc[o2][bb] = make_float4(0, 0, 0, 0);
      zacc[o2][bb] = 0.f;
    }

  if constexpr (WEIGHTED) {
#pragma unroll
    for (int o2 = 0; o2 < 2; ++o2)
#pragma unroll
      for (int bb = 0; bb < 8; ++bb)
        vreg[o2][bb] = *(const float4*)(
            vs + ((size_t)(b0 + bb) * 32 + op + o2 * 16) * 16 + dq * 4);
  }

  auto stageW = [&](int i, int nb) {
    const float4* Wi = Wg + (size_t)i * 1024;
#pragma unroll
    for (int k = 0; k < 2; ++k) {
      const int p   = k * 512 + t;
      const int src = (p & ~7) | ((p & 7) ^ ((p >> 3) & 7));
      GLOAD_LDS16(Wi + src, &Wbuf[nb][(k * 512 + wv * 64) * 4]);
    }
  };

  auto stageX = [&](int sw) {
    // xall f4 index p: i = p>>7, b = (p>>1)&63, h = p&1; linear dest
#pragma unroll
    for (int k = 0; k < 2; ++k) {
      const int p = k * 512 + t;
      const int i = p >> 7, b = (p >> 1) & 63, h = p & 1;
      GLOAD_LDS16(xg + ((size_t)b * IC + i0 + sw * 8 + i) * 2 + h,
                  &xall[(k * 512 + wv * 64) * 4]);
    }
  };

  stageX(0);
  stageW(i0, 0);
  int cur = 0;

#pragma unroll 1
  for (int sw = 0; sw < NSW; ++sw) {
#pragma unroll 1
    for (int j = 0; j < 8; ++j) {
      const int ii = sw * 8 + j;

      __syncthreads();                          // drains stage issued last iter
      if (ii + 1 < CI) stageW(i0 + ii + 1, cur ^ 1);

      // Full W fragment for both o-halves: W[i] read exactly once per wave.
      const float* Wb = &Wbuf[cur][0];
      float4 wr[2][8];
#pragma unroll
      for (int o2 = 0; o2 < 2; ++o2) {
        const int jb = (op + o2 * 16) * 32 + dq * 8;
#pragma unroll
        for (int r = 0; r < 8; ++r)
          wr[o2][r] = *(const float4*)&Wb[(jb + (r ^ rot)) * 4];
      }

#pragma unroll
      for (int bb = 0; bb < 8; ++bb) {
        const float* xp = &xall[(j * 128 + (b0 + bb) * 2) * 4];
        const float4 xa = *(const float4*)xp;        // wave-wide broadcast
        const float4 xc = *(const float4*)(xp + 4);  // wave-wide broadcast
#pragma unroll
        for (int o2 = 0; o2 < 2; ++o2) {
          float4 u;
          u.x = dot8(wr[o2][0], wr[o2][1], xa, xc);
          u.y = dot8(wr[o2][2], wr[o2][3], xa, xc);
          u.z = dot8(wr[o2][4], wr[o2][5], xa, xc);
          u.w = dot8(wr[o2][6], wr[o2][7], xa, xc);
          if constexpr (!WEIGHTED) {
            acc[o2][bb].x += u.x; acc[o2][bb].y += u.y;
            acc[o2][bb].z += u.z; acc[o2][bb].w += u.w;
          } else {
            const float4 vv = vreg[o2][bb];
            float pd = u.x * vv.x + u.y * vv.y + u.z * vv.z + u.w * vv.w;
            pd += __shfl_xor(pd, 1);          // reduce over dq (lane bits 0-1)
            pd += __shfl_xor(pd, 2);
            const float p = __expf(pd);       // unnormalized c
            acc[o2][bb].x = fmaf(p, u.x, acc[o2][bb].x);
            acc[o2][bb].y = fmaf(p, u.y, acc[o2][bb].y);
            acc[o2][bb].z = fmaf(p, u.z, acc[o2][bb].z);
            acc[o2][bb].w = fmaf(p, u.w, acc[o2][bb].w);
            zacc[o2][bb] += p;
          }
        }
      }
      cur ^= 1;
    }
    if (sw + 1 < NSW) {
      __syncthreads();              // all waves done reading xall window
      stageX(sw + 1);               // drained by next top-of-iteration barrier
    }
  }

  // epilogue: part[ch][b][o][d] f4-coalesced; zpart[ch][b*32+o] (dq==0)
  float4* part4 = (float4*)part;
#pragma unroll
  for (int o2 = 0; o2 < 2; ++o2)
#pragma unroll
    for (int bb = 0; bb < 8; ++bb) {
      const int b = b0 + bb;
      const int o = op + o2 * 16;
      part4[((size_t)ch * 64 + b) * 128 + o * 4 + dq] = acc[o2][bb];
      if constexpr (WEIGHTED) {
        if (dq == 0) zpart[(size_t)ch * 2048 + b * 32 + o] = zacc[o2][bb];
      }
    }
}

// ---------------------------------------------------------------------------
// Reduce s partials over chunks, normalize, squash.
// PASS 0: s*=1/2048, vs[g]  = v ; PASS 1: s*=rz, vs[g] += v ;
// PASS 2: s*=rz, out[g] = v.   grid 128 x 256; g = b*512 + o*16 + d.
// ---------------------------------------------------------------------------
template<int PASS, int NCH>
__global__ __launch_bounds__(256) void reduceSquash(
    const float* __restrict__ part, const float* __restrict__ rz,
    float* __restrict__ vsio, float* __restrict__ out)
{
  const int g = blockIdx.x * 256 + threadIdx.x;
  float s = 0.f;
#pragma unroll 8
  for (int ch = 0; ch < NCH; ++ch) s += part[(size_t)ch * 32768 + g];
  if constexpr (PASS == 0) s *= (1.f / 2048.f);
  else                     s *= rz[g >> 4];

  float sq = s * s;
#pragma unroll
  for (int k = 1; k < 16; k <<= 1) sq += __shfl_xor(sq, k);   // sum over d
  const float f = (sq / (1.f + sq)) * rsqrtf(sq + 1e-9f);
  const float v = s * f;

  if constexpr (PASS == 0)      vsio[g] = v;
  else if constexpr (PASS == 1) vsio[g] += v;
  else                          out[g] = v;
}

// ---------------------------------------------------------------------------
// Z reduction: rz[b*32+o] = 1 / sum_ch zpart. grid 8 x 256.
// ---------------------------------------------------------------------------
template<int NCH>
__global__ __launch_bounds__(256) void zredK(
    const float* __restrict__ zpart, float* __restrict__ rz)
{
  const int j = blockIdx.x * 256 + threadIdx.x;
  float zs = 0.f;
#pragma unroll 8
  for (int ch = 0; ch < NCH; ++ch) zs += zpart[(size_t)ch * 2048 + j];
  rz[j] = 1.f / zs;
}

// ---------------------------------------------------------------------------
extern "C" void kernel_launch(void* const* d_in, const int* in_sizes, int n_in,
                              void* d_out, int out_size, void* d_ws, size_t ws_size,
                              hipStream_t stream) {
  (void)in_sizes; (void)n_in; (void)out_size;
  const float* x = (const float*)d_in[0];
  const float* W = (const float*)d_in[1];
  float* out = (float*)d_out;
  float* ws  = (float*)d_ws;

  auto run = [&](auto tag) {
    constexpr int NCH = decltype(tag)::value;
    float* part  = ws;                                 // [NCH][64][32][16]
    float* zpart = part + (size_t)NCH * 32768;         // [NCH][2048]
    float* rz    = zpart + (size_t)NCH * 2048;         // [2048]
    float* vsb   = rz + 2048;                          // vs running sum [32768]

    const dim3 gF(NCH), bF(512), b256(256), gR(128);
    // pass 1: uniform c -> v1 (vs = v1)
    fusedK<false, NCH><<<gF, bF, 0, stream>>>(x, W, nullptr, part, nullptr);
    reduceSquash<0, NCH><<<gR, b256, 0, stream>>>(part, nullptr, vsb, nullptr);
    // pass 2: p = exp(u.v1) -> v2; vs = v1+v2
    fusedK<true, NCH><<<gF, bF, 0, stream>>>(x, W, vsb, part, zpart);
    zredK<NCH><<<dim3(8), b256, 0, stream>>>(zpart, rz);
    reduceSquash<1, NCH><<<gR, b256, 0, stream>>>(part, rz, vsb, nullptr);
    // pass 3: p = exp(u.(v1+v2)) -> v3 = output
    fusedK<true, NCH><<<gF, bF, 0, stream>>>(x, W, vsb, part, zpart);
    zredK<NCH><<<dim3(8), b256, 0, stream>>>(zpart, rz);
    reduceSquash<2, NCH><<<gR, b256, 0, stream>>>(part, rz, nullptr, out);
  };

  const size_t need256 =
      ((size_t)256 * 32768 + 256ul * 2048 + 2048 + 32768) * 4;
  if (ws_size >= need256) run(std::integral_constant<int, 256>{});
  else                    run(std::integral_constant<int, 64>{});
}

// Round 12
// 210.914 us; speedup vs baseline: 1.1240x; 1.1240x over previous
//
#include <hip/hip_runtime.h>
#include <math.h>

#define B_ 64
#define IC 2048
#define OC 32
#define OD 16
#define ID 8

#define GLOAD_LDS16(gp, lp)                                                       \
  __builtin_amdgcn_global_load_lds((const __attribute__((address_space(1))) void*)(gp), \
                                   (__attribute__((address_space(3))) void*)(lp), \
                                   16, 0, 0)

__device__ __forceinline__ float dot8(const float4 w0, const float4 w1,
                                      const float4 xa, const float4 xb) {
  return w0.x*xa.x + w0.y*xa.y + w0.z*xa.z + w0.w*xa.w
       + w1.x*xb.x + w1.y*xb.y + w1.z*xb.z + w1.w*xb.w;
}

// ---------------------------------------------------------------------------
// Fused routing pass (b_k = u.(v1+...+vk) algebra; unnormalized p=exp(u.vs),
// Z applied in reduceSquash).
//
// R12 = R8 geometry (proven: VGPR 60, no spill) with x moved OFF the LDS pipe:
//  - grid = 4*NCH XCD-remapped (xcd=bid&7, q=bid>>3, ch=(q>>2)*8+xcd, bh=q&3);
//    block = 512 threads = 8 waves; wave: og=wv>>2 (o-half), bset=wv&3 (4 b's).
//    Lane: op=lane>>2 -> o=og*16+op; dq=lane&3 -> d in [dq*4,dq*4+4).
//  - W[i] (16KB) double-buffered via global_load_lds, source XOR-swizzled
//    (involution p -> (p&~7)|((p&7)^((p>>3)&7))); per-thread 8 ds_read_b128.
//  - x[b][i][0..8) loaded as plain GLOBAL float4 loads (wave-uniform address
//    -> one 16B L1 request; vmcnt-tracked, NOT scalarized to s_load since the
//    address isn't provably uniform -> no SMEM/lgkmcnt mixing), PREFETCHED
//    one iteration ahead into xn[4][2] registers. The next iteration's
//    __syncthreads vmcnt(0) drain hits already-completed loads (latency
//    absorbed under ~3K cycles of compute). This halves LDS-pipe issue per
//    thread-iter (16 -> 8 reads for 128 FMAs), which R8's counters showed
//    was the larger serialized term (LDS 5.1K vs VALU 2.6K cyc per CU-iter).
//  - NEVER pass a 2nd __launch_bounds__ arg (R3/R9: VGPR cap -> spill);
//    amdgpu_waves_per_eu is ignored for this shape (R11).
// ---------------------------------------------------------------------------
template<bool WEIGHTED, int NCH>
__global__ __launch_bounds__(512) void fusedK(
    const float* __restrict__ x, const float* __restrict__ W,
    const float* __restrict__ vs, float* __restrict__ part,
    float* __restrict__ zpart)
{
  constexpr int CI = IC / NCH;
  const int t    = threadIdx.x;
  const int xcd  = blockIdx.x & 7;
  const int q    = blockIdx.x >> 3;
  const int ch   = (q >> 2) * 8 + xcd;
  const int bh   = q & 3;
  const int lane = t & 63;
  const int wv   = t >> 6;
  const int og   = wv >> 2;
  const int bset = wv & 3;
  const int op   = lane >> 2;
  const int dq   = lane & 3;
  const int o    = og * 16 + op;
  const int rot  = lane & 7;
  const int i0   = ch * CI;
  const int jb   = o * 32 + dq * 8;      // thread's W f4 base
  const int bl0  = bset * 4;
  const int b0   = bh * 16 + bl0;        // wave's first b

  __shared__ float Wbuf[2][4096];        // 2 x 16 KB

  const float4* Wg = (const float4*)W;

  float4 acc[4];
  float  zacc[4];
  float4 vreg[4];
  float4 xn[4][2];                       // next-iter x, prefetched
#pragma unroll
  for (int k = 0; k < 4; ++k) { acc[k] = make_float4(0,0,0,0); zacc[k] = 0.f; }

  if constexpr (WEIGHTED) {
#pragma unroll
    for (int bb = 0; bb < 4; ++bb)
      vreg[bb] = *(const float4*)(vs + ((size_t)(b0 + bb) * 32 + o) * 16 + dq * 4);
  }

  auto stageW = [&](int i, int nb) {
    const float4* Wi = Wg + (size_t)i * 1024;
#pragma unroll
    for (int k = 0; k < 2; ++k) {
      const int p   = k * 512 + t;
      const int src = (p & ~7) | ((p & 7) ^ ((p >> 3) & 7));
      GLOAD_LDS16(Wi + src, &Wbuf[nb][(k * 512 + wv * 64) * 4]);
    }
  };

  auto loadX = [&](int i) {
#pragma unroll
    for (int bb = 0; bb < 4; ++bb) {
      const float* p = x + ((size_t)(b0 + bb) * IC + i) * ID;
      xn[bb][0] = *(const float4*)p;        // wave-uniform addr -> 1 L1 req
      xn[bb][1] = *(const float4*)(p + 4);
    }
  };

  loadX(i0);
  stageW(i0, 0);
  int cur = 0;

#pragma unroll 1
  for (int ii = 0; ii < CI; ++ii) {
    __syncthreads();                          // drains stage+loads of last iter
    if (ii + 1 < CI) stageW(i0 + ii + 1, cur ^ 1);

    const float* Wb = &Wbuf[cur][0];
    float4 wr[8];
#pragma unroll
    for (int r = 0; r < 8; ++r)
      wr[r] = *(const float4*)&Wb[(jb + (r ^ rot)) * 4];

#pragma unroll
    for (int bb = 0; bb < 4; ++bb) {
      const float4 xa = xn[bb][0];
      const float4 xc = xn[bb][1];
      float4 u;
      u.x = dot8(wr[0], wr[1], xa, xc);
      u.y = dot8(wr[2], wr[3], xa, xc);
      u.z = dot8(wr[4], wr[5], xa, xc);
      u.w = dot8(wr[6], wr[7], xa, xc);
      if constexpr (!WEIGHTED) {
        acc[bb].x += u.x; acc[bb].y += u.y; acc[bb].z += u.z; acc[bb].w += u.w;
      } else {
        const float4 vv = vreg[bb];
        float pd = u.x * vv.x + u.y * vv.y + u.z * vv.z + u.w * vv.w;
        pd += __shfl_xor(pd, 1);              // reduce over dq (lane bits 0-1)
        pd += __shfl_xor(pd, 2);
        const float p = __expf(pd);           // unnormalized c
        acc[bb].x = fmaf(p, u.x, acc[bb].x);
        acc[bb].y = fmaf(p, u.y, acc[bb].y);
        acc[bb].z = fmaf(p, u.z, acc[bb].z);
        acc[bb].w = fmaf(p, u.w, acc[bb].w);
        zacc[bb] += p;
      }
    }

    if (ii + 1 < CI) loadX(i0 + ii + 1);      // prefetch next x (WAR on xn ok)
    cur ^= 1;
  }

  // epilogue: part[ch][b][o][d] f4-coalesced; zpart[ch][b*32+o] (dq==0)
  float4* part4 = (float4*)part;
#pragma unroll
  for (int bb = 0; bb < 4; ++bb) {
    const int b = b0 + bb;
    part4[((size_t)ch * 64 + b) * 128 + o * 4 + dq] = acc[bb];
    if constexpr (WEIGHTED) {
      if (dq == 0) zpart[(size_t)ch * 2048 + b * 32 + o] = zacc[bb];
    }
  }
}

// ---------------------------------------------------------------------------
// Reduce s partials over chunks, normalize, squash.
// PASS 0: s*=1/2048, vs[g]  = v ; PASS 1: s*=rz, vs[g] += v ;
// PASS 2: s*=rz, out[g] = v.   grid 128 x 256; g = b*512 + o*16 + d.
// ---------------------------------------------------------------------------
template<int PASS, int NCH>
__global__ __launch_bounds__(256) void reduceSquash(
    const float* __restrict__ part, const float* __restrict__ rz,
    float* __restrict__ vsio, float* __restrict__ out)
{
  const int g = blockIdx.x * 256 + threadIdx.x;
  float s = 0.f;
#pragma unroll 8
  for (int ch = 0; ch < NCH; ++ch) s += part[(size_t)ch * 32768 + g];
  if constexpr (PASS == 0) s *= (1.f / 2048.f);
  else                     s *= rz[g >> 4];

  float sq = s * s;
#pragma unroll
  for (int k = 1; k < 16; k <<= 1) sq += __shfl_xor(sq, k);   // sum over d
  const float f = (sq / (1.f + sq)) * rsqrtf(sq + 1e-9f);
  const float v = s * f;

  if constexpr (PASS == 0)      vsio[g] = v;
  else if constexpr (PASS == 1) vsio[g] += v;
  else                          out[g] = v;
}

// ---------------------------------------------------------------------------
// Z reduction: rz[b*32+o] = 1 / sum_ch zpart. grid 8 x 256.
// ---------------------------------------------------------------------------
template<int NCH>
__global__ __launch_bounds__(256) void zredK(
    const float* __restrict__ zpart, float* __restrict__ rz)
{
  const int j = blockIdx.x * 256 + threadIdx.x;
  float zs = 0.f;
#pragma unroll 8
  for (int ch = 0; ch < NCH; ++ch) zs += zpart[(size_t)ch * 2048 + j];
  rz[j] = 1.f / zs;
}

// ---------------------------------------------------------------------------
extern "C" void kernel_launch(void* const* d_in, const int* in_sizes, int n_in,
                              void* d_out, int out_size, void* d_ws, size_t ws_size,
                              hipStream_t stream) {
  (void)in_sizes; (void)n_in; (void)out_size;
  const float* x = (const float*)d_in[0];
  const float* W = (const float*)d_in[1];
  float* out = (float*)d_out;
  float* ws  = (float*)d_ws;

  auto run = [&](auto tag) {
    constexpr int NCH = decltype(tag)::value;
    float* part  = ws;                                 // [NCH][64][32][16]
    float* zpart = part + (size_t)NCH * 32768;         // [NCH][2048]
    float* rz    = zpart + (size_t)NCH * 2048;         // [2048]
    float* vsb   = rz + 2048;                          // vs running sum [32768]

    const dim3 gF(4 * NCH), bF(512), b256(256), gR(128);
    // pass 1: uniform c -> v1 (vs = v1)
    fusedK<false, NCH><<<gF, bF, 0, stream>>>(x, W, nullptr, part, nullptr);
    reduceSquash<0, NCH><<<gR, b256, 0, stream>>>(part, nullptr, vsb, nullptr);
    // pass 2: p = exp(u.v1) -> v2; vs = v1+v2
    fusedK<true, NCH><<<gF, bF, 0, stream>>>(x, W, vsb, part, zpart);
    zredK<NCH><<<dim3(8), b256, 0, stream>>>(zpart, rz);
    reduceSquash<1, NCH><<<gR, b256, 0, stream>>>(part, rz, vsb, nullptr);
    // pass 3: p = exp(u.(v1+v2)) -> v3 = output
    fusedK<true, NCH><<<gF, bF, 0, stream>>>(x, W, vsb, part, zpart);
    zredK<NCH><<<dim3(8), b256, 0, stream>>>(zpart, rz);
    reduceSquash<2, NCH><<<gR, b256, 0, stream>>>(part, rz, nullptr, out);
  };

  const size_t need256 =
      ((size_t)256 * 32768 + 256ul * 2048 + 2048 + 32768) * 4;
  if (ws_size >= need256) run(std::integral_constant<int, 256>{});
  else                    run(std::integral_constant<int, 64>{});
}

// Round 13
// 174.140 us; speedup vs baseline: 1.3614x; 1.2112x over previous
//
#include <hip/hip_runtime.h>
#include <math.h>

#define B_ 64
#define IC 2048
#define OC 32
#define OD 16
#define ID 8

#define GLOAD_LDS16(gp, lp)                                                       \
  __builtin_amdgcn_global_load_lds((const __attribute__((address_space(1))) void*)(gp), \
                                   (__attribute__((address_space(3))) void*)(lp), \
                                   16, 0, 0)

__device__ __forceinline__ float dot8(const float4 w0, const float4 w1,
                                      const float4 xa, const float4 xb) {
  return w0.x*xa.x + w0.y*xa.y + w0.z*xa.z + w0.w*xa.w
       + w1.x*xb.x + w1.y*xb.y + w1.z*xb.z + w1.w*xb.w;
}

// ---------------------------------------------------------------------------
// Fused routing pass (b_k = u.(v1+...+vk); unnormalized p=exp(u.vs); Z in
// reduceSquash).
//
// R13 geometry: grid = 2*NCH (xcd=bid&7, q=bid>>3, bh=q&1, ch=(q>>1)*8+xcd),
// block = 512 threads = 8 waves; wave wv owns b in [bh*32+wv*4, +4).
// Lane: op=lane>>2, dq=lane&3. Thread covers BOTH o-halves {op, op+16}
// sequentially (wr only 8 f4 live) x 4 d x 4 b = 512 FMA per i against
// 16 W reads + 16 x broadcast reads -> ds_read/FMA = 0.0625, half of R8.
// Each wave consumes W[i] exactly once (no intra-wave duplication).
//
// Staging: W in 2-i phases (32KB, double-buffered 64KB) -> barrier per 2 i's
// (halves convoy); x window [8i][32b][8m] (8KB, dbuf) staged one phase ahead
// at window boundaries. LDS 80KB -> 2 blocks/CU, 16 waves.
// W source XOR-swizzled (involution p->(p&~7)|((p&7)^((p>>3)&7)), verified
// consistent with read index jb+(r^rot) since rot==(addr>>3)&7).
// VGPR budget: acc32+vreg32+wr32+temps ~ 115 < 128 cap (R9-R11: cap is hard).
// ---------------------------------------------------------------------------
template<bool WEIGHTED, int NCH>
__global__ __launch_bounds__(512) void fusedK(
    const float* __restrict__ x, const float* __restrict__ W,
    const float* __restrict__ vs, float* __restrict__ part,
    float* __restrict__ zpart)
{
  constexpr int CI  = IC / NCH;        // 8 (NCH=256) or 32 (NCH=64)
  constexpr int NPH = CI / 2;          // 2-i phases
  constexpr int NSW = CI / 8;          // 8-i x-windows
  const int t    = threadIdx.x;
  const int xcd  = blockIdx.x & 7;
  const int q    = blockIdx.x >> 3;
  const int bh   = q & 1;
  const int ch   = (q >> 1) * 8 + xcd;
  const int lane = t & 63;
  const int wv   = t >> 6;
  const int op   = lane >> 2;
  const int dq   = lane & 3;
  const int rot  = lane & 7;
  const int i0   = ch * CI;
  const int bl0  = wv * 4;
  const int b0   = bh * 32 + bl0;

  __shared__ float Wbuf[2][8192];      // 2 x 32 KB (2048 f4 each, 2 i's)
  __shared__ float xall[2][2048];      // 2 x [8i][32b][8m] = 2 x 8 KB

  const float4* Wg = (const float4*)W;
  const float4* xg = (const float4*)x;

  float4 acc[2][4];
  float  zacc[2][4];
  float4 vreg[2][4];
#pragma unroll
  for (int o2 = 0; o2 < 2; ++o2)
#pragma unroll
    for (int bb = 0; bb < 4; ++bb) {
      acc[o2][bb] = make_float4(0, 0, 0, 0);
      zacc[o2][bb] = 0.f;
    }

  if constexpr (WEIGHTED) {
#pragma unroll
    for (int o2 = 0; o2 < 2; ++o2)
#pragma unroll
      for (int bb = 0; bb < 4; ++bb)
        vreg[o2][bb] = *(const float4*)(
            vs + ((size_t)(b0 + bb) * 32 + op + o2 * 16) * 16 + dq * 4);
  }

  auto stageW2 = [&](int ph, int nb) {        // stage W[i0+ph*2 .. +2)
    const float4* Wi = Wg + (size_t)(i0 + ph * 2) * 1024;
#pragma unroll
    for (int k = 0; k < 4; ++k) {
      const int p   = k * 512 + t;
      const int src = (p & ~7) | ((p & 7) ^ ((p >> 3) & 7));
      GLOAD_LDS16(Wi + src, &Wbuf[nb][(k * 512 + wv * 64) * 4]);
    }
  };

  auto stageX = [&](int sw, int xb) {         // stage x window sw (8 i, 32 b)
    const int i = t >> 6, b = (t >> 1) & 31, h = t & 1;
    GLOAD_LDS16(xg + ((size_t)(bh * 32 + b) * IC + i0 + sw * 8 + i) * 2 + h,
                &xall[xb][wv * 64 * 4]);
  };

  stageX(0, 0);
  stageW2(0, 0);
  int cur = 0;

#pragma unroll 1
  for (int ph = 0; ph < NPH; ++ph) {
    __syncthreads();                          // drains stages issued last phase
    if (ph + 1 < NPH) stageW2(ph + 1, cur ^ 1);
    if constexpr (NSW > 1) {
      if ((ph & 3) == 3 && ph + 1 < NPH)      // last phase of window: prefetch
        stageX((ph + 1) >> 2, ((ph + 1) >> 2) & 1);
    }

    const float* Wb = &Wbuf[cur][0];
    const float* Xw = (NSW > 1) ? &xall[(ph >> 2) & 1][0] : &xall[0][0];

#pragma unroll
    for (int ip = 0; ip < 2; ++ip) {
      const int iw = ((ph * 2 + ip) & 7);     // i within x window
#pragma unroll
      for (int o2 = 0; o2 < 2; ++o2) {
        const int jb = ip * 1024 + (op + o2 * 16) * 32 + dq * 8;
        float4 wr[8];
#pragma unroll
        for (int r = 0; r < 8; ++r)
          wr[r] = *(const float4*)&Wb[(jb + (r ^ rot)) * 4];

#pragma unroll
        for (int bb = 0; bb < 4; ++bb) {
          const float* xp = &Xw[(iw * 32 + bl0 + bb) * 8];
          const float4 xa = *(const float4*)xp;        // wave-wide broadcast
          const float4 xc = *(const float4*)(xp + 4);  // wave-wide broadcast
          float4 u;
          u.x = dot8(wr[0], wr[1], xa, xc);
          u.y = dot8(wr[2], wr[3], xa, xc);
          u.z = dot8(wr[4], wr[5], xa, xc);
          u.w = dot8(wr[6], wr[7], xa, xc);
          if constexpr (!WEIGHTED) {
            acc[o2][bb].x += u.x; acc[o2][bb].y += u.y;
            acc[o2][bb].z += u.z; acc[o2][bb].w += u.w;
          } else {
            const float4 vv = vreg[o2][bb];
            float pd = u.x * vv.x + u.y * vv.y + u.z * vv.z + u.w * vv.w;
            pd += __shfl_xor(pd, 1);          // reduce over dq (lane bits 0-1)
            pd += __shfl_xor(pd, 2);
            const float p = __expf(pd);       // unnormalized c
            acc[o2][bb].x = fmaf(p, u.x, acc[o2][bb].x);
            acc[o2][bb].y = fmaf(p, u.y, acc[o2][bb].y);
            acc[o2][bb].z = fmaf(p, u.z, acc[o2][bb].z);
            acc[o2][bb].w = fmaf(p, u.w, acc[o2][bb].w);
            zacc[o2][bb] += p;
          }
        }
      }
    }
    cur ^= 1;
  }

  // epilogue: part[ch][b][o][d] f4-coalesced; zpart[ch][b*32+o] (dq==0)
  float4* part4 = (float4*)part;
#pragma unroll
  for (int o2 = 0; o2 < 2; ++o2)
#pragma unroll
    for (int bb = 0; bb < 4; ++bb) {
      const int b = b0 + bb;
      const int o = op + o2 * 16;
      part4[((size_t)ch * 64 + b) * 128 + o * 4 + dq] = acc[o2][bb];
      if constexpr (WEIGHTED) {
        if (dq == 0) zpart[(size_t)ch * 2048 + b * 32 + o] = zacc[o2][bb];
      }
    }
}

// ---------------------------------------------------------------------------
// Reduce s partials over chunks, normalize, squash.
// PASS 0: s*=1/2048, vs[g]  = v ; PASS 1: s*=rz, vs[g] += v ;
// PASS 2: s*=rz, out[g] = v.   grid 128 x 256; g = b*512 + o*16 + d.
// ---------------------------------------------------------------------------
template<int PASS, int NCH>
__global__ __launch_bounds__(256) void reduceSquash(
    const float* __restrict__ part, const float* __restrict__ rz,
    float* __restrict__ vsio, float* __restrict__ out)
{
  const int g = blockIdx.x * 256 + threadIdx.x;
  float s = 0.f;
#pragma unroll 8
  for (int ch = 0; ch < NCH; ++ch) s += part[(size_t)ch * 32768 + g];
  if constexpr (PASS == 0) s *= (1.f / 2048.f);
  else                     s *= rz[g >> 4];

  float sq = s * s;
#pragma unroll
  for (int k = 1; k < 16; k <<= 1) sq += __shfl_xor(sq, k);   // sum over d
  const float f = (sq / (1.f + sq)) * rsqrtf(sq + 1e-9f);
  const float v = s * f;

  if constexpr (PASS == 0)      vsio[g] = v;
  else if constexpr (PASS == 1) vsio[g] += v;
  else                          out[g] = v;
}

// ---------------------------------------------------------------------------
// Z reduction: rz[b*32+o] = 1 / sum_ch zpart. grid 8 x 256.
// ---------------------------------------------------------------------------
template<int NCH>
__global__ __launch_bounds__(256) void zredK(
    const float* __restrict__ zpart, float* __restrict__ rz)
{
  const int j = blockIdx.x * 256 + threadIdx.x;
  float zs = 0.f;
#pragma unroll 8
  for (int ch = 0; ch < NCH; ++ch) zs += zpart[(size_t)ch * 2048 + j];
  rz[j] = 1.f / zs;
}

// ---------------------------------------------------------------------------
extern "C" void kernel_launch(void* const* d_in, const int* in_sizes, int n_in,
                              void* d_out, int out_size, void* d_ws, size_t ws_size,
                              hipStream_t stream) {
  (void)in_sizes; (void)n_in; (void)out_size;
  const float* x = (const float*)d_in[0];
  const float* W = (const float*)d_in[1];
  float* out = (float*)d_out;
  float* ws  = (float*)d_ws;

  auto run = [&](auto tag) {
    constexpr int NCH = decltype(tag)::value;
    float* part  = ws;                                 // [NCH][64][32][16]
    float* zpart = part + (size_t)NCH * 32768;         // [NCH][2048]
    float* rz    = zpart + (size_t)NCH * 2048;         // [2048]
    float* vsb   = rz + 2048;                          // vs running sum [32768]

    const dim3 gF(2 * NCH), bF(512), b256(256), gR(128);
    // pass 1: uniform c -> v1 (vs = v1)
    fusedK<false, NCH><<<gF, bF, 0, stream>>>(x, W, nullptr, part, nullptr);
    reduceSquash<0, NCH><<<gR, b256, 0, stream>>>(part, nullptr, vsb, nullptr);
    // pass 2: p = exp(u.v1) -> v2; vs = v1+v2
    fusedK<true, NCH><<<gF, bF, 0, stream>>>(x, W, vsb, part, zpart);
    zredK<NCH><<<dim3(8), b256, 0, stream>>>(zpart, rz);
    reduceSquash<1, NCH><<<gR, b256, 0, stream>>>(part, rz, vsb, nullptr);
    // pass 3: p = exp(u.(v1+v2)) -> v3 = output
    fusedK<true, NCH><<<gF, bF, 0, stream>>>(x, W, vsb, part, zpart);
    zredK<NCH><<<dim3(8), b256, 0, stream>>>(zpart, rz);
    reduceSquash<2, NCH><<<gR, b256, 0, stream>>>(part, rz, nullptr, out);
  };

  const size_t need256 =
      ((size_t)256 * 32768 + 256ul * 2048 + 2048 + 32768) * 4;
  if (ws_size >= need256) run(std::integral_constant<int, 256>{});
  else                    run(std::integral_constant<int, 64>{});
}

// Round 14
// 140.474 us; speedup vs baseline: 1.6876x; 1.2397x over previous
//
#include <hip/hip_runtime.h>
#include <math.h>

#define B_ 64
#define IC 2048
#define OC 32
#define OD 16
#define ID 8

typedef __attribute__((ext_vector_type(8)))  short s16x8;
typedef __attribute__((ext_vector_type(16))) float f32x16;

#define GLOAD_LDS16(gp, lp)                                                       \
  __builtin_amdgcn_global_load_lds((const __attribute__((address_space(1))) void*)(gp), \
                                   (__attribute__((address_space(3))) void*)(lp), \
                                   16, 0, 0)

__device__ __forceinline__ unsigned short f2bf(float f) {      // RNE f32->bf16
  unsigned u = __float_as_uint(f);
  return (unsigned short)((u + 0x7fffu + ((u >> 16) & 1u)) >> 16);
}
__device__ __forceinline__ float bf2f(unsigned short h) {
  return __uint_as_float(((unsigned)h) << 16);
}
__device__ __forceinline__ f32x16 mfma16(s16x8 a, s16x8 b, f32x16 c) {
  return __builtin_amdgcn_mfma_f32_32x32x16_bf16(a, b, c, 0, 0, 0);
}
__device__ __forceinline__ float dot8(const float4 w0, const float4 w1,
                                      const float4 xa, const float4 xb) {
  return w0.x*xa.x + w0.y*xa.y + w0.z*xa.z + w0.w*xa.w
       + w1.x*xb.x + w1.y*xb.y + w1.z*xb.z + w1.w*xb.w;
}

// ---------------------------------------------------------------------------
// One-time split-bf16 conversions.
// Wbf layout: [i][half(hi=0,lo=1)][o][d][m] ushort; xb: [i][half][b][m].
// ---------------------------------------------------------------------------
__global__ __launch_bounds__(256) void convW(const float* __restrict__ W,
                                             unsigned short* __restrict__ Wbf) {
  const int e4 = blockIdx.x * 256 + threadIdx.x;    // 2,097,152 f4 threads
  const float4 v = ((const float4*)W)[e4];
  const int i = e4 >> 10;
  const int r = (e4 & 1023) << 2;
  ushort4 h, l;
  h.x = f2bf(v.x); l.x = f2bf(v.x - bf2f(h.x));
  h.y = f2bf(v.y); l.y = f2bf(v.y - bf2f(h.y));
  h.z = f2bf(v.z); l.z = f2bf(v.z - bf2f(h.z));
  h.w = f2bf(v.w); l.w = f2bf(v.w - bf2f(h.w));
  *(ushort4*)&Wbf[(size_t)i * 8192 + r]        = h;
  *(ushort4*)&Wbf[(size_t)i * 8192 + 4096 + r] = l;
}

__global__ __launch_bounds__(256) void convX(const float* __restrict__ x,
                                             unsigned short* __restrict__ xb) {
  const int idx = blockIdx.x * 256 + threadIdx.x;   // 262,144 = 64b*2048i*2
  const int m2 = idx & 1, i = (idx >> 1) & 2047, b = idx >> 12;
  const float4 v = *(const float4*)(x + (size_t)b * 16384 + i * 8 + m2 * 4);
  ushort4 h, l;
  h.x = f2bf(v.x); l.x = f2bf(v.x - bf2f(h.x));
  h.y = f2bf(v.y); l.y = f2bf(v.y - bf2f(h.y));
  h.z = f2bf(v.z); l.z = f2bf(v.z - bf2f(h.z));
  h.w = f2bf(v.w); l.w = f2bf(v.w - bf2f(h.w));
  *(ushort4*)&xb[(size_t)i * 1024 + b * 8 + m2 * 4]       = h;
  *(ushort4*)&xb[(size_t)i * 1024 + 512 + b * 8 + m2 * 4] = l;
}

// ---------------------------------------------------------------------------
// MFMA fused routing pass. u = W.x via chained 32x32x16 bf16 MFMAs:
//   A rows 0-15 = (oA, d), 16-31 = (oA+1, d); k0-7 paired with xhi, k8-15
//   with xlo; chain1 A=Whi, chain2 A=Wlo -> u = (Whi+Wlo).(xhi+xlo).
// C layout [m74/m101]: col=lane&31=b, row=(reg&3)+8*(reg>>2)+4*(lane>>5);
// regs 0-7 -> oA, 8-15 -> oB. pd over d = 8 in-lane fma + 1 shfl_xor(32).
// grid = 2*NCH (oh=bid&1, ch=bid>>1), block 512 = 8 waves; wave wv owns
// o_local {2wv, 2wv+1}; 2 b-tiles of 32 per wave.
// W-LDS [half][o_local 16][d][m] 8KB/i dbuf; x-LDS [half][b][m] 2KB/i dbuf.
// ---------------------------------------------------------------------------
template<bool WEIGHTED, int NCH>
__global__ __launch_bounds__(512) void fusedM(
    const unsigned short* __restrict__ Wbf, const unsigned short* __restrict__ xb,
    const float* __restrict__ vs, float* __restrict__ part,
    float* __restrict__ zpart)
{
  constexpr int CI = IC / NCH;
  const int t    = threadIdx.x;
  const int oh   = blockIdx.x & 1;
  const int ch   = blockIdx.x >> 1;
  const int lane = t & 63;
  const int wv   = t >> 6;
  const int l31  = lane & 31;
  const int hb   = lane >> 5;
  const int i0   = ch * CI;
  const int aoff = (2 * wv + (l31 >> 4)) * 128 + (lane & 15) * 8;

  __shared__ unsigned short Wl[2][4096];   // 2 x 8 KB
  __shared__ unsigned short Xl[2][1024];   // 2 x 2 KB

  f32x16 acc0 = (f32x16)0.0f, acc1 = (f32x16)0.0f;
  float zA0 = 0.f, zB0 = 0.f, zA1 = 0.f, zB1 = 0.f;
  float vs0[16], vs1[16];

  if constexpr (WEIGHTED) {
#pragma unroll
    for (int r = 0; r < 16; ++r) {
      const int o = oh * 16 + 2 * wv + (r >= 8 ? 1 : 0);
      const int d = (r & 3) + 8 * ((r >> 2) & 1) + 4 * hb;
      vs0[r] = vs[(size_t)(l31 * 32 + o) * 16 + d];
      vs1[r] = vs[(size_t)((32 + l31) * 32 + o) * 16 + d];
    }
  }

  auto stageW = [&](int i, int nb) {
    GLOAD_LDS16(Wbf + (size_t)i * 8192 + (t >> 8) * 4096 + oh * 2048 + (t & 255) * 8,
                &Wl[nb][t * 8]);
  };
  auto stageX = [&](int i, int nb) {
    if (t < 128) GLOAD_LDS16(xb + (size_t)i * 1024 + t * 8, &Xl[nb][t * 8]);
  };

  stageW(i0, 0);
  stageX(i0, 0);
  int cur = 0;

#pragma unroll 1
  for (int ii = 0; ii < CI; ++ii) {
    __syncthreads();                         // drains stages issued last iter
    if (ii + 1 < CI) { stageW(i0 + ii + 1, cur ^ 1); stageX(i0 + ii + 1, cur ^ 1); }

    const s16x8 aHi = *(const s16x8*)&Wl[cur][aoff];
    const s16x8 aLo = *(const s16x8*)&Wl[cur][aoff + 2048];
    const s16x8 b0  = *(const s16x8*)&Xl[cur][hb * 512 + l31 * 8];
    const s16x8 b1  = *(const s16x8*)&Xl[cur][hb * 512 + 256 + l31 * 8];

    if constexpr (!WEIGHTED) {
      acc0 = mfma16(aHi, b0, acc0); acc0 = mfma16(aLo, b0, acc0);
      acc1 = mfma16(aHi, b1, acc1); acc1 = mfma16(aLo, b1, acc1);
    } else {
      {
        f32x16 u = mfma16(aHi, b0, (f32x16)0.0f); u = mfma16(aLo, b0, u);
        float pdA = 0.f, pdB = 0.f;
#pragma unroll
        for (int r = 0; r < 8; ++r)  pdA = fmaf(u[r], vs0[r], pdA);
#pragma unroll
        for (int r = 8; r < 16; ++r) pdB = fmaf(u[r], vs0[r], pdB);
        pdA += __shfl_xor(pdA, 32);
        pdB += __shfl_xor(pdB, 32);
        const float pA = __expf(pdA), pB = __expf(pdB);
#pragma unroll
        for (int r = 0; r < 8; ++r)  acc0[r] = fmaf(pA, u[r], acc0[r]);
#pragma unroll
        for (int r = 8; r < 16; ++r) acc0[r] = fmaf(pB, u[r], acc0[r]);
        zA0 += pA; zB0 += pB;
      }
      {
        f32x16 u = mfma16(aHi, b1, (f32x16)0.0f); u = mfma16(aLo, b1, u);
        float pdA = 0.f, pdB = 0.f;
#pragma unroll
        for (int r = 0; r < 8; ++r)  pdA = fmaf(u[r], vs1[r], pdA);
#pragma unroll
        for (int r = 8; r < 16; ++r) pdB = fmaf(u[r], vs1[r], pdB);
        pdA += __shfl_xor(pdA, 32);
        pdB += __shfl_xor(pdB, 32);
        const float pA = __expf(pdA), pB = __expf(pdB);
#pragma unroll
        for (int r = 0; r < 8; ++r)  acc1[r] = fmaf(pA, u[r], acc1[r]);
#pragma unroll
        for (int r = 8; r < 16; ++r) acc1[r] = fmaf(pB, u[r], acc1[r]);
        zA1 += pA; zB1 += pB;
      }
    }
    cur ^= 1;
  }

  // epilogue: part[ch][b][o][d]
  float* bp = part + (size_t)ch * 32768;
#pragma unroll
  for (int r = 0; r < 16; ++r) {
    const int o = oh * 16 + 2 * wv + (r >= 8 ? 1 : 0);
    const int d = (r & 3) + 8 * ((r >> 2) & 1) + 4 * hb;
    bp[(size_t)(l31 * 32 + o) * 16 + d]        = acc0[r];
    bp[(size_t)((32 + l31) * 32 + o) * 16 + d] = acc1[r];
  }
  if constexpr (WEIGHTED) {
    if (lane < 32) {
      const int ob = oh * 16 + 2 * wv;
      zpart[(size_t)ch * 2048 + lane * 32 + ob]            = zA0;
      zpart[(size_t)ch * 2048 + lane * 32 + ob + 1]        = zB0;
      zpart[(size_t)ch * 2048 + (32 + lane) * 32 + ob]     = zA1;
      zpart[(size_t)ch * 2048 + (32 + lane) * 32 + ob + 1] = zB1;
    }
  }
}

// ---------------------------------------------------------------------------
// fp32 fallback (R8 kernel, proven): used only if ws_size is too small for
// the split-bf16 buffers.
// ---------------------------------------------------------------------------
template<bool WEIGHTED, int NCH>
__global__ __launch_bounds__(512) void fusedF32(
    const float* __restrict__ x, const float* __restrict__ W,
    const float* __restrict__ vs, float* __restrict__ part,
    float* __restrict__ zpart)
{
  constexpr int CI  = IC / NCH;
  constexpr int NSW = CI / 8;
  const int t    = threadIdx.x;
  const int xcd  = blockIdx.x & 7;
  const int q    = blockIdx.x >> 3;
  const int ch   = (q >> 2) * 8 + xcd;
  const int bh   = q & 3;
  const int lane = t & 63;
  const int wv   = t >> 6;
  const int og   = wv >> 2;
  const int bset = wv & 3;
  const int op   = lane >> 2;
  const int dq   = lane & 3;
  const int o    = og * 16 + op;
  const int rot  = lane & 7;
  const int i0   = ch * CI;
  const int jb   = o * 32 + dq * 8;
  const int bl0  = bset * 4;
  const int b0   = bh * 16 + bl0;

  __shared__ float Wbuf[2][4096];
  __shared__ float xall[1024];

  const float4* Wg = (const float4*)W;
  const float4* xg = (const float4*)x;

  float4 acc[4];
  float  zacc[4];
  float4 vreg[4];
#pragma unroll
  for (int k = 0; k < 4; ++k) { acc[k] = make_float4(0,0,0,0); zacc[k] = 0.f; }

  if constexpr (WEIGHTED) {
#pragma unroll
    for (int bb = 0; bb < 4; ++bb)
      vreg[bb] = *(const float4*)(vs + ((size_t)(b0 + bb) * 32 + o) * 16 + dq * 4);
  }

  auto stageW = [&](int i, int nb) {
    const float4* Wi = Wg + (size_t)i * 1024;
#pragma unroll
    for (int k = 0; k < 2; ++k) {
      const int p   = wv * 128 + k * 64 + lane;
      const int src = (p & ~7) | ((p & 7) ^ ((p >> 3) & 7));
      GLOAD_LDS16(Wi + src, &Wbuf[nb][(wv * 128 + k * 64) * 4]);
    }
  };
  auto stageX = [&](int sw) {
    if (t < 256) {
      const int b = t >> 4, r = t & 15;
      const int ia = i0 + sw * 8 + (r >> 1);
      GLOAD_LDS16(xg + ((size_t)(bh * 16 + b) * IC + ia) * 2 + (r & 1),
                  &xall[(wv * 64) * 4]);
    }
  };

  stageX(0);
  stageW(i0, 0);
  int cur = 0;

#pragma unroll 1
  for (int sw = 0; sw < NSW; ++sw) {
#pragma unroll 1
    for (int j = 0; j < 8; ++j) {
      const int ii = sw * 8 + j;
      __syncthreads();
      if (ii + 1 < CI) stageW(i0 + ii + 1, cur ^ 1);

      const float* Wb = &Wbuf[cur][0];
      float4 wr[8];
#pragma unroll
      for (int r = 0; r < 8; ++r)
        wr[r] = *(const float4*)&Wb[(jb + (r ^ rot)) * 4];

#pragma unroll
      for (int bb = 0; bb < 4; ++bb) {
        const int bl = bl0 + bb;
        const float4 xa = *(const float4*)&xall[bl * 64 + j * 8];
        const float4 xc = *(const float4*)&xall[bl * 64 + j * 8 + 4];
        float4 u;
        u.x = dot8(wr[0], wr[1], xa, xc);
        u.y = dot8(wr[2], wr[3], xa, xc);
        u.z = dot8(wr[4], wr[5], xa, xc);
        u.w = dot8(wr[6], wr[7], xa, xc);
        if constexpr (!WEIGHTED) {
          acc[bb].x += u.x; acc[bb].y += u.y; acc[bb].z += u.z; acc[bb].w += u.w;
        } else {
          const float4 vv = vreg[bb];
          float pd = u.x * vv.x + u.y * vv.y + u.z * vv.z + u.w * vv.w;
          pd += __shfl_xor(pd, 1);
          pd += __shfl_xor(pd, 2);
          const float p = __expf(pd);
          acc[bb].x = fmaf(p, u.x, acc[bb].x);
          acc[bb].y = fmaf(p, u.y, acc[bb].y);
          acc[bb].z = fmaf(p, u.z, acc[bb].z);
          acc[bb].w = fmaf(p, u.w, acc[bb].w);
          zacc[bb] += p;
        }
      }
      cur ^= 1;
    }
    if (sw + 1 < NSW) { __syncthreads(); stageX(sw + 1); }
  }

  float4* part4 = (float4*)part;
#pragma unroll
  for (int bb = 0; bb < 4; ++bb) {
    const int b = b0 + bb;
    part4[((size_t)ch * 64 + b) * 128 + o * 4 + dq] = acc[bb];
    if constexpr (WEIGHTED) {
      if (dq == 0) zpart[(size_t)ch * 2048 + b * 32 + o] = zacc[bb];
    }
  }
}

// ---------------------------------------------------------------------------
// Reduce s partials over chunks, normalize, squash.
// PASS 0: s*=1/2048, vs[g]=v ; PASS 1: s*=rz, vs[g]+=v ; PASS 2: out[g]=v.
// ---------------------------------------------------------------------------
template<int PASS, int NCH>
__global__ __launch_bounds__(256) void reduceSquash(
    const float* __restrict__ part, const float* __restrict__ rz,
    float* __restrict__ vsio, float* __restrict__ out)
{
  const int g = blockIdx.x * 256 + threadIdx.x;
  float s = 0.f;
#pragma unroll 8
  for (int ch = 0; ch < NCH; ++ch) s += part[(size_t)ch * 32768 + g];
  if constexpr (PASS == 0) s *= (1.f / 2048.f);
  else                     s *= rz[g >> 4];

  float sq = s * s;
#pragma unroll
  for (int k = 1; k < 16; k <<= 1) sq += __shfl_xor(sq, k);
  const float f = (sq / (1.f + sq)) * rsqrtf(sq + 1e-9f);
  const float v = s * f;

  if constexpr (PASS == 0)      vsio[g] = v;
  else if constexpr (PASS == 1) vsio[g] += v;
  else                          out[g] = v;
}

template<int NCH>
__global__ __launch_bounds__(256) void zredK(
    const float* __restrict__ zpart, float* __restrict__ rz)
{
  const int j = blockIdx.x * 256 + threadIdx.x;
  float zs = 0.f;
#pragma unroll 8
  for (int ch = 0; ch < NCH; ++ch) zs += zpart[(size_t)ch * 2048 + j];
  rz[j] = 1.f / zs;
}

// ---------------------------------------------------------------------------
extern "C" void kernel_launch(void* const* d_in, const int* in_sizes, int n_in,
                              void* d_out, int out_size, void* d_ws, size_t ws_size,
                              hipStream_t stream) {
  (void)in_sizes; (void)n_in; (void)out_size;
  const float* x = (const float*)d_in[0];
  const float* W = (const float*)d_in[1];
  float* out = (float*)d_out;
  float* ws  = (float*)d_ws;

  const size_t WBF_US = (size_t)IC * 8192;   // split-bf16 W elements
  const size_t XB_US  = (size_t)IC * 1024;   // split-bf16 x elements

  auto runM = [&](auto tag) {
    constexpr int NCH = decltype(tag)::value;
    float* part  = ws;
    float* zpart = part + (size_t)NCH * 32768;
    float* rz    = zpart + (size_t)NCH * 2048;
    float* vsb   = rz + 2048;
    unsigned short* Wbf = (unsigned short*)(vsb + 32768);
    unsigned short* xbp = Wbf + WBF_US;

    const dim3 bF(512), b256(256), gF(2 * NCH), gR(128);
    convW<<<dim3(8192), b256, 0, stream>>>(W, Wbf);
    convX<<<dim3(1024), b256, 0, stream>>>(x, xbp);
    // pass 1: uniform c -> v1
    fusedM<false, NCH><<<gF, bF, 0, stream>>>(Wbf, xbp, nullptr, part, nullptr);
    reduceSquash<0, NCH><<<gR, b256, 0, stream>>>(part, nullptr, vsb, nullptr);
    // pass 2: p = exp(u.v1) -> v2; vs = v1+v2
    fusedM<true, NCH><<<gF, bF, 0, stream>>>(Wbf, xbp, vsb, part, zpart);
    zredK<NCH><<<dim3(8), b256, 0, stream>>>(zpart, rz);
    reduceSquash<1, NCH><<<gR, b256, 0, stream>>>(part, rz, vsb, nullptr);
    // pass 3: p = exp(u.(v1+v2)) -> v3 = out
    fusedM<true, NCH><<<gF, bF, 0, stream>>>(Wbf, xbp, vsb, part, zpart);
    zredK<NCH><<<dim3(8), b256, 0, stream>>>(zpart, rz);
    reduceSquash<2, NCH><<<gR, b256, 0, stream>>>(part, rz, nullptr, out);
  };

  auto runF = [&](auto tag) {
    constexpr int NCH = decltype(tag)::value;
    float* part  = ws;
    float* zpart = part + (size_t)NCH * 32768;
    float* rz    = zpart + (size_t)NCH * 2048;
    float* vsb   = rz + 2048;

    const dim3 gF(4 * NCH), bF(512), b256(256), gR(128);
    fusedF32<false, NCH><<<gF, bF, 0, stream>>>(x, W, nullptr, part, nullptr);
    reduceSquash<0, NCH><<<gR, b256, 0, stream>>>(part, nullptr, vsb, nullptr);
    fusedF32<true, NCH><<<gF, bF, 0, stream>>>(x, W, vsb, part, zpart);
    zredK<NCH><<<dim3(8), b256, 0, stream>>>(zpart, rz);
    reduceSquash<1, NCH><<<gR, b256, 0, stream>>>(part, rz, vsb, nullptr);
    fusedF32<true, NCH><<<gF, bF, 0, stream>>>(x, W, vsb, part, zpart);
    zredK<NCH><<<dim3(8), b256, 0, stream>>>(zpart, rz);
    reduceSquash<2, NCH><<<gR, b256, 0, stream>>>(part, rz, nullptr, out);
  };

  auto needM = [&](size_t nch) -> size_t {
    return (nch * 32768 + nch * 2048 + 2048 + 32768) * 4 + (WBF_US + XB_US) * 2;
  };
  const size_t needF256 = ((size_t)256 * 32768 + 256ul * 2048 + 2048 + 32768) * 4;

  if      (ws_size >= needM(256)) runM(std::integral_constant<int, 256>{});
  else if (ws_size >= needM(128)) runM(std::integral_constant<int, 128>{});
  else if (ws_size >= needM(64))  runM(std::integral_constant<int, 64>{});
  else if (ws_size >= needF256)   runF(std::integral_constant<int, 256>{});
  else                            runF(std::integral_constant<int, 64>{});
}

// Round 15
// 99.399 us; speedup vs baseline: 2.3850x; 1.4132x over previous
//
#include <hip/hip_runtime.h>
#include <math.h>

#define B_ 64
#define IC 2048
#define OC 32
#define OD 16
#define ID 8

typedef __attribute__((ext_vector_type(8)))  short s16x8;
typedef __attribute__((ext_vector_type(16))) float f32x16;

#define GLOAD_LDS16(gp, lp)                                                       \
  __builtin_amdgcn_global_load_lds((const __attribute__((address_space(1))) void*)(gp), \
                                   (__attribute__((address_space(3))) void*)(lp), \
                                   16, 0, 0)

__device__ __forceinline__ unsigned short f2bf(float f) {      // RNE f32->bf16
  unsigned u = __float_as_uint(f);
  return (unsigned short)((u + 0x7fffu + ((u >> 16) & 1u)) >> 16);
}
__device__ __forceinline__ float bf2f(unsigned short h) {
  return __uint_as_float(((unsigned)h) << 16);
}
__device__ __forceinline__ f32x16 mfma16(s16x8 a, s16x8 b, f32x16 c) {
  return __builtin_amdgcn_mfma_f32_32x32x16_bf16(a, b, c, 0, 0, 0);
}
__device__ __forceinline__ float dot8(const float4 w0, const float4 w1,
                                      const float4 xa, const float4 xb) {
  return w0.x*xa.x + w0.y*xa.y + w0.z*xa.z + w0.w*xa.w
       + w1.x*xb.x + w1.y*xb.y + w1.z*xb.z + w1.w*xb.w;
}

// ---------------------------------------------------------------------------
// One-time split-bf16 conversions (proven R14).
// Wbf: [i][half][o][d][m] ushort; xb: [i][half][b][m] ushort.
// ---------------------------------------------------------------------------
__global__ __launch_bounds__(256) void convW(const float* __restrict__ W,
                                             unsigned short* __restrict__ Wbf) {
  const int e4 = blockIdx.x * 256 + threadIdx.x;
  const float4 v = ((const float4*)W)[e4];
  const int i = e4 >> 10;
  const int r = (e4 & 1023) << 2;
  ushort4 h, l;
  h.x = f2bf(v.x); l.x = f2bf(v.x - bf2f(h.x));
  h.y = f2bf(v.y); l.y = f2bf(v.y - bf2f(h.y));
  h.z = f2bf(v.z); l.z = f2bf(v.z - bf2f(h.z));
  h.w = f2bf(v.w); l.w = f2bf(v.w - bf2f(h.w));
  *(ushort4*)&Wbf[(size_t)i * 8192 + r]        = h;
  *(ushort4*)&Wbf[(size_t)i * 8192 + 4096 + r] = l;
}

__global__ __launch_bounds__(256) void convX(const float* __restrict__ x,
                                             unsigned short* __restrict__ xb) {
  const int idx = blockIdx.x * 256 + threadIdx.x;
  const int m2 = idx & 1, i = (idx >> 1) & 2047, b = idx >> 12;
  const float4 v = *(const float4*)(x + (size_t)b * 16384 + i * 8 + m2 * 4);
  ushort4 h, l;
  h.x = f2bf(v.x); l.x = f2bf(v.x - bf2f(h.x));
  h.y = f2bf(v.y); l.y = f2bf(v.y - bf2f(h.y));
  h.z = f2bf(v.z); l.z = f2bf(v.z - bf2f(h.z));
  h.w = f2bf(v.w); l.w = f2bf(v.w - bf2f(h.w));
  *(ushort4*)&xb[(size_t)i * 1024 + b * 8 + m2 * 4]       = h;
  *(ushort4*)&xb[(size_t)i * 1024 + 512 + b * 8 + m2 * 4] = l;
}

// ---------------------------------------------------------------------------
// R15 MFMA routing pass: NO LDS, NO barriers. Each wave = one 32x32 tile
// (o-pair x 32 b) and loads its A/B fragments DIRECTLY global->VGPR as
// per-lane 16B slices (coalesced 512B wave segments), prefetched 1 i ahead.
// u = (Whi+Wlo).(xhi+xlo) via 2 chained MFMAs (A k8-15 duplicates k0-7;
// B k0-7 = xhi, k8-15 = xlo) — verified R14 (absmax 2e-3).
//
// grid = 8*NCH, bid = q*NCH + ch (NCH%8==0 -> same-ch blocks share XCD L2
// for the W window). block 256 = 4 waves; slot s = q*4+wv in [0,32):
// opair = s>>1 (o in {2*opair, 2*opair+1}), bt = s&1 (b tile).
//
// part is stored in MFMA-register ("scrambled") order for coalesced stores:
//   idx(ch, s, r, hb, l31) = s*1024 + r*64 + hb*32 + l31   (element r of the
//   C fragment; per-store-inst lanes form 2x128B segments). rsqM decodes.
// zpart scrambled too: z[ch][ (s*2+oo)*32 + l31 ].
// ---------------------------------------------------------------------------
template<bool WEIGHTED, int NCH>
__global__ __launch_bounds__(256) void fusedM(
    const unsigned short* __restrict__ Wbf, const unsigned short* __restrict__ xb,
    const float* __restrict__ vs, float* __restrict__ part,
    float* __restrict__ zpart)
{
  constexpr int CI = IC / NCH;
  const int t     = threadIdx.x;
  const int ch    = blockIdx.x % NCH;
  const int q     = blockIdx.x / NCH;
  const int lane  = t & 63;
  const int wv    = t >> 6;
  const int s     = q * 4 + wv;          // 0..31
  const int opair = s >> 1;
  const int bt    = s & 1;
  const int l31   = lane & 31;
  const int hb    = lane >> 5;
  const int i0    = ch * CI;

  const unsigned short* ap =
      Wbf + (size_t)i0 * 8192 + opair * 256 + (l31 >> 4) * 128 + (lane & 15) * 8;
  const unsigned short* bp =
      xb + (size_t)i0 * 1024 + hb * 512 + bt * 256 + l31 * 8;

  f32x16 acc = (f32x16)0.0f;
  float zA = 0.f, zB = 0.f;
  float vsr[16];

  if constexpr (WEIGHTED) {
#pragma unroll
    for (int r = 0; r < 16; ++r) {
      const int o = opair * 2 + (r >= 8 ? 1 : 0);
      const int d = (r & 3) + 8 * ((r >> 2) & 1) + 4 * hb;
      vsr[r] = vs[(size_t)((bt * 32 + l31) * 32 + o) * 16 + d];
    }
  }

  s16x8 aH = *(const s16x8*)ap;
  s16x8 aL = *(const s16x8*)(ap + 4096);
  s16x8 bv = *(const s16x8*)bp;

#pragma unroll 2
  for (int ii = 0; ii < CI; ++ii) {
    s16x8 naH = aH, naL = aL, nbv = bv;
    if (ii + 1 < CI) {
      naH = *(const s16x8*)(ap + (size_t)(ii + 1) * 8192);
      naL = *(const s16x8*)(ap + (size_t)(ii + 1) * 8192 + 4096);
      nbv = *(const s16x8*)(bp + (size_t)(ii + 1) * 1024);
    }

    if constexpr (!WEIGHTED) {
      acc = mfma16(aH, bv, acc);
      acc = mfma16(aL, bv, acc);
    } else {
      f32x16 u = mfma16(aH, bv, (f32x16)0.0f);
      u = mfma16(aL, bv, u);
      float pdA = 0.f, pdB = 0.f;
#pragma unroll
      for (int r = 0; r < 8; ++r)  pdA = fmaf(u[r], vsr[r], pdA);
#pragma unroll
      for (int r = 8; r < 16; ++r) pdB = fmaf(u[r], vsr[r], pdB);
      pdA += __shfl_xor(pdA, 32);            // add other hb's 8 d's
      pdB += __shfl_xor(pdB, 32);
      const float pA = __expf(pdA), pB = __expf(pdB);
#pragma unroll
      for (int r = 0; r < 8; ++r)  acc[r] = fmaf(pA, u[r], acc[r]);
#pragma unroll
      for (int r = 8; r < 16; ++r) acc[r] = fmaf(pB, u[r], acc[r]);
      zA += pA; zB += pB;
    }

    aH = naH; aL = naL; bv = nbv;
  }

  // scrambled, coalesced epilogue (2x128B segments per store inst)
  float* op = part + (size_t)ch * 32768;
#pragma unroll
  for (int r = 0; r < 16; ++r)
    op[(s * 16 + r) * 64 + hb * 32 + l31] = acc[r];
  if constexpr (WEIGHTED) {
    if (lane < 32) {
      zpart[(size_t)ch * 2048 + (s * 2 + 0) * 32 + lane] = zA;
      zpart[(size_t)ch * 2048 + (s * 2 + 1) * 32 + lane] = zB;
    }
  }
}

// ---------------------------------------------------------------------------
// Reduce+squash over scrambled part. grid 64 blocks x 512 (block = (s,oo):
// 32 (b,o) pairs x 16 d's). Fuses the Z reduction (threads t<32).
// tid bits: s = tid>>10, oo = (tid>>9)&1, rr = (tid>>6)&7, hb = (tid>>5)&1,
// l31 = tid&31;  b = (s&1)*32+l31, o = (s>>1)*2+oo, d = (rr&3)+8*(rr>>2)+4*hb.
// PASS 0: scale 1/2048, vs[g]=v; PASS 1: scale 1/Z, vs[g]+=v; PASS 2: out.
// ---------------------------------------------------------------------------
template<int PASS, int NCH>
__global__ __launch_bounds__(512) void rsqM(
    const float* __restrict__ part, const float* __restrict__ zpart,
    float* __restrict__ vsio, float* __restrict__ out)
{
  __shared__ float rzs[32];
  __shared__ float sqs[512];
  const int t   = threadIdx.x;
  const int blk = blockIdx.x;
  const int s   = blk >> 1, oo = blk & 1;
  const int l31 = t & 31, hb = (t >> 5) & 1, rr = t >> 6;
  const size_t tid = (size_t)blk * 512 + t;

  float acc = 0.f;
#pragma unroll 8
  for (int ch = 0; ch < NCH; ++ch) acc += part[(size_t)ch * 32768 + tid];

  if constexpr (PASS == 0) {
    if (t < 32) rzs[t] = 1.f / 2048.f;
  } else {
    if (t < 32) {
      float zs = 0.f;
#pragma unroll 8
      for (int ch = 0; ch < NCH; ++ch)
        zs += zpart[(size_t)ch * 2048 + (s * 2 + oo) * 32 + t];
      rzs[t] = 1.f / zs;
    }
  }
  __syncthreads();
  const float sv = acc * rzs[l31];
  sqs[t] = sv * sv;
  __syncthreads();
  float sq = 0.f;
#pragma unroll
  for (int k = 0; k < 16; ++k) sq += sqs[l31 + k * 32];
  const float f = (sq / (1.f + sq)) * rsqrtf(sq + 1e-9f);
  const float v = sv * f;

  const int b = (s & 1) * 32 + l31;
  const int o = (s >> 1) * 2 + oo;
  const int d = (rr & 3) + 8 * (rr >> 2) + 4 * hb;
  const int g = (b * 32 + o) * 16 + d;
  if constexpr (PASS == 0)      vsio[g] = v;
  else if constexpr (PASS == 1) vsio[g] += v;
  else                          out[g] = v;
}

// ---------------------------------------------------------------------------
// fp32 fallback path (R8 kernel + old reducers), for small ws only.
// ---------------------------------------------------------------------------
template<bool WEIGHTED, int NCH>
__global__ __launch_bounds__(512) void fusedF32(
    const float* __restrict__ x, const float* __restrict__ W,
    const float* __restrict__ vs, float* __restrict__ part,
    float* __restrict__ zpart)
{
  constexpr int CI  = IC / NCH;
  constexpr int NSW = CI / 8;
  const int t    = threadIdx.x;
  const int xcd  = blockIdx.x & 7;
  const int q    = blockIdx.x >> 3;
  const int ch   = (q >> 2) * 8 + xcd;
  const int bh   = q & 3;
  const int lane = t & 63;
  const int wv   = t >> 6;
  const int og   = wv >> 2;
  const int bset = wv & 3;
  const int op   = lane >> 2;
  const int dq   = lane & 3;
  const int o    = og * 16 + op;
  const int rot  = lane & 7;
  const int i0   = ch * CI;
  const int jb   = o * 32 + dq * 8;
  const int bl0  = bset * 4;
  const int b0   = bh * 16 + bl0;

  __shared__ float Wbuf[2][4096];
  __shared__ float xall[1024];

  const float4* Wg = (const float4*)W;
  const float4* xg = (const float4*)x;

  float4 acc[4];
  float  zacc[4];
  float4 vreg[4];
#pragma unroll
  for (int k = 0; k < 4; ++k) { acc[k] = make_float4(0,0,0,0); zacc[k] = 0.f; }

  if constexpr (WEIGHTED) {
#pragma unroll
    for (int bb = 0; bb < 4; ++bb)
      vreg[bb] = *(const float4*)(vs + ((size_t)(b0 + bb) * 32 + o) * 16 + dq * 4);
  }

  auto stageW = [&](int i, int nb) {
    const float4* Wi = Wg + (size_t)i * 1024;
#pragma unroll
    for (int k = 0; k < 2; ++k) {
      const int p   = wv * 128 + k * 64 + lane;
      const int src = (p & ~7) | ((p & 7) ^ ((p >> 3) & 7));
      GLOAD_LDS16(Wi + src, &Wbuf[nb][(wv * 128 + k * 64) * 4]);
    }
  };
  auto stageX = [&](int sw) {
    if (t < 256) {
      const int b = t >> 4, r = t & 15;
      const int ia = i0 + sw * 8 + (r >> 1);
      GLOAD_LDS16(xg + ((size_t)(bh * 16 + b) * IC + ia) * 2 + (r & 1),
                  &xall[(wv * 64) * 4]);
    }
  };

  stageX(0);
  stageW(i0, 0);
  int cur = 0;

#pragma unroll 1
  for (int sw = 0; sw < NSW; ++sw) {
#pragma unroll 1
    for (int j = 0; j < 8; ++j) {
      const int ii = sw * 8 + j;
      __syncthreads();
      if (ii + 1 < CI) stageW(i0 + ii + 1, cur ^ 1);

      const float* Wb = &Wbuf[cur][0];
      float4 wr[8];
#pragma unroll
      for (int r = 0; r < 8; ++r)
        wr[r] = *(const float4*)&Wb[(jb + (r ^ rot)) * 4];

#pragma unroll
      for (int bb = 0; bb < 4; ++bb) {
        const int bl = bl0 + bb;
        const float4 xa = *(const float4*)&xall[bl * 64 + j * 8];
        const float4 xc = *(const float4*)&xall[bl * 64 + j * 8 + 4];
        float4 u;
        u.x = dot8(wr[0], wr[1], xa, xc);
        u.y = dot8(wr[2], wr[3], xa, xc);
        u.z = dot8(wr[4], wr[5], xa, xc);
        u.w = dot8(wr[6], wr[7], xa, xc);
        if constexpr (!WEIGHTED) {
          acc[bb].x += u.x; acc[bb].y += u.y; acc[bb].z += u.z; acc[bb].w += u.w;
        } else {
          const float4 vv = vreg[bb];
          float pd = u.x * vv.x + u.y * vv.y + u.z * vv.z + u.w * vv.w;
          pd += __shfl_xor(pd, 1);
          pd += __shfl_xor(pd, 2);
          const float p = __expf(pd);
          acc[bb].x = fmaf(p, u.x, acc[bb].x);
          acc[bb].y = fmaf(p, u.y, acc[bb].y);
          acc[bb].z = fmaf(p, u.z, acc[bb].z);
          acc[bb].w = fmaf(p, u.w, acc[bb].w);
          zacc[bb] += p;
        }
      }
      cur ^= 1;
    }
    if (sw + 1 < NSW) { __syncthreads(); stageX(sw + 1); }
  }

  float4* part4 = (float4*)part;
#pragma unroll
  for (int bb = 0; bb < 4; ++bb) {
    const int b = b0 + bb;
    part4[((size_t)ch * 64 + b) * 128 + o * 4 + dq] = acc[bb];
    if constexpr (WEIGHTED) {
      if (dq == 0) zpart[(size_t)ch * 2048 + b * 32 + o] = zacc[bb];
    }
  }
}

template<int PASS, int NCH>
__global__ __launch_bounds__(256) void reduceSquash(
    const float* __restrict__ part, const float* __restrict__ rz,
    float* __restrict__ vsio, float* __restrict__ out)
{
  const int g = blockIdx.x * 256 + threadIdx.x;
  float s = 0.f;
#pragma unroll 8
  for (int ch = 0; ch < NCH; ++ch) s += part[(size_t)ch * 32768 + g];
  if constexpr (PASS == 0) s *= (1.f / 2048.f);
  else                     s *= rz[g >> 4];

  float sq = s * s;
#pragma unroll
  for (int k = 1; k < 16; k <<= 1) sq += __shfl_xor(sq, k);
  const float f = (sq / (1.f + sq)) * rsqrtf(sq + 1e-9f);
  const float v = s * f;

  if constexpr (PASS == 0)      vsio[g] = v;
  else if constexpr (PASS == 1) vsio[g] += v;
  else                          out[g] = v;
}

template<int NCH>
__global__ __launch_bounds__(256) void zredK(
    const float* __restrict__ zpart, float* __restrict__ rz)
{
  const int j = blockIdx.x * 256 + threadIdx.x;
  float zs = 0.f;
#pragma unroll 8
  for (int ch = 0; ch < NCH; ++ch) zs += zpart[(size_t)ch * 2048 + j];
  rz[j] = 1.f / zs;
}

// ---------------------------------------------------------------------------
extern "C" void kernel_launch(void* const* d_in, const int* in_sizes, int n_in,
                              void* d_out, int out_size, void* d_ws, size_t ws_size,
                              hipStream_t stream) {
  (void)in_sizes; (void)n_in; (void)out_size;
  const float* x = (const float*)d_in[0];
  const float* W = (const float*)d_in[1];
  float* out = (float*)d_out;
  float* ws  = (float*)d_ws;

  const size_t WBF_US = (size_t)IC * 8192;
  const size_t XB_US  = (size_t)IC * 1024;

  auto runM = [&](auto tag) {
    constexpr int NCH = decltype(tag)::value;
    float* part  = ws;                                  // [NCH][32768] scrambled
    float* zpart = part + (size_t)NCH * 32768;          // [NCH][2048] scrambled
    float* vsb   = zpart + (size_t)NCH * 2048;          // [32768] standard
    unsigned short* Wbf = (unsigned short*)(vsb + 32768);
    unsigned short* xbp = Wbf + WBF_US;

    const dim3 b256(256), b512(512), gF(8 * NCH), gR(64);
    convW<<<dim3(8192), b256, 0, stream>>>(W, Wbf);
    convX<<<dim3(1024), b256, 0, stream>>>(x, xbp);
    // pass 1: uniform c -> v1
    fusedM<false, NCH><<<gF, b256, 0, stream>>>(Wbf, xbp, nullptr, part, nullptr);
    rsqM<0, NCH><<<gR, b512, 0, stream>>>(part, nullptr, vsb, nullptr);
    // pass 2: p = exp(u.v1) -> v2; vs = v1+v2
    fusedM<true, NCH><<<gF, b256, 0, stream>>>(Wbf, xbp, vsb, part, zpart);
    rsqM<1, NCH><<<gR, b512, 0, stream>>>(part, zpart, vsb, nullptr);
    // pass 3: p = exp(u.(v1+v2)) -> v3 = out
    fusedM<true, NCH><<<gF, b256, 0, stream>>>(Wbf, xbp, vsb, part, zpart);
    rsqM<2, NCH><<<gR, b512, 0, stream>>>(part, zpart, nullptr, out);
  };

  auto runF = [&](auto tag) {
    constexpr int NCH = decltype(tag)::value;
    float* part  = ws;
    float* zpart = part + (size_t)NCH * 32768;
    float* rz    = zpart + (size_t)NCH * 2048;
    float* vsb   = rz + 2048;

    const dim3 gF(4 * NCH), bF(512), b256(256), gR(128);
    fusedF32<false, NCH><<<gF, bF, 0, stream>>>(x, W, nullptr, part, nullptr);
    reduceSquash<0, NCH><<<gR, b256, 0, stream>>>(part, nullptr, vsb, nullptr);
    fusedF32<true, NCH><<<gF, bF, 0, stream>>>(x, W, vsb, part, zpart);
    zredK<NCH><<<dim3(8), b256, 0, stream>>>(zpart, rz);
    reduceSquash<1, NCH><<<gR, b256, 0, stream>>>(part, rz, vsb, nullptr);
    fusedF32<true, NCH><<<gF, bF, 0, stream>>>(x, W, vsb, part, zpart);
    zredK<NCH><<<dim3(8), b256, 0, stream>>>(zpart, rz);
    reduceSquash<2, NCH><<<gR, b256, 0, stream>>>(part, rz, nullptr, out);
  };

  auto needM = [&](size_t nch) -> size_t {
    return (nch * 32768 + nch * 2048 + 32768) * 4 + (WBF_US + XB_US) * 2;
  };
  const size_t needF256 = ((size_t)256 * 32768 + 256ul * 2048 + 2048 + 32768) * 4;

  if      (ws_size >= needM(128)) runM(std::integral_constant<int, 128>{});
  else if (ws_size >= needM(64))  runM(std::integral_constant<int, 64>{});
  else if (ws_size >= needF256)   runF(std::integral_constant<int, 256>{});
  else                            runF(std::integral_constant<int, 64>{});
}

// Round 16
// 96.632 us; speedup vs baseline: 2.4533x; 1.0286x over previous
//
#include <hip/hip_runtime.h>
#include <math.h>

#define B_ 64
#define IC 2048
#define OC 32
#define OD 16
#define ID 8

typedef __attribute__((ext_vector_type(8)))  short s16x8;
typedef __attribute__((ext_vector_type(16))) float f32x16;

#define GLOAD_LDS16(gp, lp)                                                       \
  __builtin_amdgcn_global_load_lds((const __attribute__((address_space(1))) void*)(gp), \
                                   (__attribute__((address_space(3))) void*)(lp), \
                                   16, 0, 0)

__device__ __forceinline__ unsigned short f2bf(float f) {      // RNE f32->bf16
  unsigned u = __float_as_uint(f);
  return (unsigned short)((u + 0x7fffu + ((u >> 16) & 1u)) >> 16);
}
__device__ __forceinline__ float bf2f(unsigned short h) {
  return __uint_as_float(((unsigned)h) << 16);
}
__device__ __forceinline__ f32x16 mfma16(s16x8 a, s16x8 b, f32x16 c) {
  return __builtin_amdgcn_mfma_f32_32x32x16_bf16(a, b, c, 0, 0, 0);
}
__device__ __forceinline__ float dot8(const float4 w0, const float4 w1,
                                      const float4 xa, const float4 xb) {
  return w0.x*xa.x + w0.y*xa.y + w0.z*xa.z + w0.w*xa.w
       + w1.x*xb.x + w1.y*xb.y + w1.z*xb.z + w1.w*xb.w;
}

// ---------------------------------------------------------------------------
// One-time split-bf16 conversions (proven R14/R15).
// Wbf: [i][half][o][d][m] ushort; xb: [i][half][b][m] ushort.
// ---------------------------------------------------------------------------
__global__ __launch_bounds__(256) void convW(const float* __restrict__ W,
                                             unsigned short* __restrict__ Wbf) {
  const int e4 = blockIdx.x * 256 + threadIdx.x;
  const float4 v = ((const float4*)W)[e4];
  const int i = e4 >> 10;
  const int r = (e4 & 1023) << 2;
  ushort4 h, l;
  h.x = f2bf(v.x); l.x = f2bf(v.x - bf2f(h.x));
  h.y = f2bf(v.y); l.y = f2bf(v.y - bf2f(h.y));
  h.z = f2bf(v.z); l.z = f2bf(v.z - bf2f(h.z));
  h.w = f2bf(v.w); l.w = f2bf(v.w - bf2f(h.w));
  *(ushort4*)&Wbf[(size_t)i * 8192 + r]        = h;
  *(ushort4*)&Wbf[(size_t)i * 8192 + 4096 + r] = l;
}

__global__ __launch_bounds__(256) void convX(const float* __restrict__ x,
                                             unsigned short* __restrict__ xb) {
  const int idx = blockIdx.x * 256 + threadIdx.x;
  const int m2 = idx & 1, i = (idx >> 1) & 2047, b = idx >> 12;
  const float4 v = *(const float4*)(x + (size_t)b * 16384 + i * 8 + m2 * 4);
  ushort4 h, l;
  h.x = f2bf(v.x); l.x = f2bf(v.x - bf2f(h.x));
  h.y = f2bf(v.y); l.y = f2bf(v.y - bf2f(h.y));
  h.z = f2bf(v.z); l.z = f2bf(v.z - bf2f(h.z));
  h.w = f2bf(v.w); l.w = f2bf(v.w - bf2f(h.w));
  *(ushort4*)&xb[(size_t)i * 1024 + b * 8 + m2 * 4]       = h;
  *(ushort4*)&xb[(size_t)i * 1024 + 512 + b * 8 + m2 * 4] = l;
}

// ---------------------------------------------------------------------------
// R16 MFMA routing pass: no LDS, no barriers (R15 structure), plus:
//  - vs kept in SCRAMBLED layout (vss[s*1024 + r*64 + hb*32 + l31]) so the
//    per-lane fragment read is 16 coalesced 256B loads (R15's standard-layout
//    gather was 16 insts x 64 distinct 4B addresses per wave).
//  - TRUE depth-2 prefetch: 3 rotating stage buffers, load(ii+2) issued
//    BEFORE compute(ii) into the slot freed at ii-1; full unroll keeps all
//    stage indices compile-time (no scratch, rule #20). In-flight distance
//    = 2 compute iters, covering L2 latency (R15's 2-buffer scheme was
//    effectively depth-1).
// grid = 8*NCH, bid = q*NCH + ch (NCH%8==0 -> same-ch blocks on one XCD).
// wave slot s = q*4+wv: opair = s>>1, bt = s&1; 32x32 tile per wave.
// part/zpart scrambled as R15 (coalesced epilogue).
// ---------------------------------------------------------------------------
template<bool WEIGHTED, int NCH>
__global__ __launch_bounds__(256) void fusedM(
    const unsigned short* __restrict__ Wbf, const unsigned short* __restrict__ xb,
    const float* __restrict__ vss, float* __restrict__ part,
    float* __restrict__ zpart)
{
  constexpr int CI = IC / NCH;
  const int t     = threadIdx.x;
  const int ch    = blockIdx.x % NCH;
  const int q     = blockIdx.x / NCH;
  const int lane  = t & 63;
  const int wv    = t >> 6;
  const int s     = q * 4 + wv;          // 0..31
  const int opair = s >> 1;
  const int bt    = s & 1;
  const int l31   = lane & 31;
  const int hb    = lane >> 5;
  const int i0    = ch * CI;

  const unsigned short* ap =
      Wbf + (size_t)i0 * 8192 + opair * 256 + (l31 >> 4) * 128 + (lane & 15) * 8;
  const unsigned short* bp =
      xb + (size_t)i0 * 1024 + hb * 512 + bt * 256 + l31 * 8;

  f32x16 acc = (f32x16)0.0f;
  float zA = 0.f, zB = 0.f;
  float vsr[16];

  if constexpr (WEIGHTED) {
    const float* vp = vss + s * 1024 + hb * 32 + l31;   // coalesced 256B/ld
#pragma unroll
    for (int r = 0; r < 16; ++r) vsr[r] = vp[r * 64];
  }

  s16x8 AH[3], AL[3], BV[3];
  AH[0] = *(const s16x8*)ap;
  AL[0] = *(const s16x8*)(ap + 4096);
  BV[0] = *(const s16x8*)bp;
  if (CI > 1) {
    AH[1] = *(const s16x8*)(ap + 8192);
    AL[1] = *(const s16x8*)(ap + 8192 + 4096);
    BV[1] = *(const s16x8*)(bp + 1024);
  }

#pragma unroll
  for (int ii = 0; ii < CI; ++ii) {
    const int cs = ii % 3;
    const int ns = (ii + 2) % 3;
    if (ii + 2 < CI) {                       // issue 2 iters ahead
      AH[ns] = *(const s16x8*)(ap + (size_t)(ii + 2) * 8192);
      AL[ns] = *(const s16x8*)(ap + (size_t)(ii + 2) * 8192 + 4096);
      BV[ns] = *(const s16x8*)(bp + (size_t)(ii + 2) * 1024);
    }

    if constexpr (!WEIGHTED) {
      acc = mfma16(AH[cs], BV[cs], acc);
      acc = mfma16(AL[cs], BV[cs], acc);
    } else {
      f32x16 u = mfma16(AH[cs], BV[cs], (f32x16)0.0f);
      u = mfma16(AL[cs], BV[cs], u);
      float pdA = 0.f, pdB = 0.f;
#pragma unroll
      for (int r = 0; r < 8; ++r)  pdA = fmaf(u[r], vsr[r], pdA);
#pragma unroll
      for (int r = 8; r < 16; ++r) pdB = fmaf(u[r], vsr[r], pdB);
      pdA += __shfl_xor(pdA, 32);            // add other hb's 8 d's
      pdB += __shfl_xor(pdB, 32);
      const float pA = __expf(pdA), pB = __expf(pdB);
#pragma unroll
      for (int r = 0; r < 8; ++r)  acc[r] = fmaf(pA, u[r], acc[r]);
#pragma unroll
      for (int r = 8; r < 16; ++r) acc[r] = fmaf(pB, u[r], acc[r]);
      zA += pA; zB += pB;
    }
  }

  // scrambled, coalesced epilogue
  float* op = part + (size_t)ch * 32768;
#pragma unroll
  for (int r = 0; r < 16; ++r)
    op[(s * 16 + r) * 64 + hb * 32 + l31] = acc[r];
  if constexpr (WEIGHTED) {
    if (lane < 32) {
      zpart[(size_t)ch * 2048 + (s * 2 + 0) * 32 + lane] = zA;
      zpart[(size_t)ch * 2048 + (s * 2 + 1) * 32 + lane] = zB;
    }
  }
}

// ---------------------------------------------------------------------------
// Reduce+squash over scrambled part; writes vss in SCRAMBLED layout
// (vss[blk*512+t] — perfectly coalesced; same coords fusedM reads).
// PASS 2 writes out in standard [b][o][d] layout (128KB once, scatter ok).
// grid 64 x 512; blk = (s,oo); t = (rr,hb,l31). Z reduction fused (t<32).
// ---------------------------------------------------------------------------
template<int PASS, int NCH>
__global__ __launch_bounds__(512) void rsqM(
    const float* __restrict__ part, const float* __restrict__ zpart,
    float* __restrict__ vss, float* __restrict__ out)
{
  __shared__ float rzs[32];
  __shared__ float sqs[512];
  const int t   = threadIdx.x;
  const int blk = blockIdx.x;
  const int s   = blk >> 1, oo = blk & 1;
  const int l31 = t & 31, hb = (t >> 5) & 1, rr = t >> 6;
  const size_t tid = (size_t)blk * 512 + t;

  float acc = 0.f;
#pragma unroll 8
  for (int ch = 0; ch < NCH; ++ch) acc += part[(size_t)ch * 32768 + tid];

  if constexpr (PASS == 0) {
    if (t < 32) rzs[t] = 1.f / 2048.f;
  } else {
    if (t < 32) {
      float zs = 0.f;
#pragma unroll 8
      for (int ch = 0; ch < NCH; ++ch)
        zs += zpart[(size_t)ch * 2048 + (s * 2 + oo) * 32 + t];
      rzs[t] = 1.f / zs;
    }
  }
  __syncthreads();
  const float sv = acc * rzs[l31];
  sqs[t] = sv * sv;
  __syncthreads();
  float sq = 0.f;
#pragma unroll
  for (int k = 0; k < 16; ++k) sq += sqs[l31 + k * 32];
  const float f = (sq / (1.f + sq)) * rsqrtf(sq + 1e-9f);
  const float v = sv * f;

  if constexpr (PASS == 0)      vss[tid] = v;
  else if constexpr (PASS == 1) vss[tid] += v;
  else {
    const int b = (s & 1) * 32 + l31;
    const int o = (s >> 1) * 2 + oo;
    const int d = (rr & 3) + 8 * (rr >> 2) + 4 * hb;
    out[(b * 32 + o) * 16 + d] = v;
  }
}

// ---------------------------------------------------------------------------
// fp32 fallback path (R8 kernel + old reducers), for small ws only.
// ---------------------------------------------------------------------------
template<bool WEIGHTED, int NCH>
__global__ __launch_bounds__(512) void fusedF32(
    const float* __restrict__ x, const float* __restrict__ W,
    const float* __restrict__ vs, float* __restrict__ part,
    float* __restrict__ zpart)
{
  constexpr int CI  = IC / NCH;
  constexpr int NSW = CI / 8;
  const int t    = threadIdx.x;
  const int xcd  = blockIdx.x & 7;
  const int q    = blockIdx.x >> 3;
  const int ch   = (q >> 2) * 8 + xcd;
  const int bh   = q & 3;
  const int lane = t & 63;
  const int wv   = t >> 6;
  const int og   = wv >> 2;
  const int bset = wv & 3;
  const int op   = lane >> 2;
  const int dq   = lane & 3;
  const int o    = og * 16 + op;
  const int rot  = lane & 7;
  const int i0   = ch * CI;
  const int jb   = o * 32 + dq * 8;
  const int bl0  = bset * 4;
  const int b0   = bh * 16 + bl0;

  __shared__ float Wbuf[2][4096];
  __shared__ float xall[1024];

  const float4* Wg = (const float4*)W;
  const float4* xg = (const float4*)x;

  float4 acc[4];
  float  zacc[4];
  float4 vreg[4];
#pragma unroll
  for (int k = 0; k < 4; ++k) { acc[k] = make_float4(0,0,0,0); zacc[k] = 0.f; }

  if constexpr (WEIGHTED) {
#pragma unroll
    for (int bb = 0; bb < 4; ++bb)
      vreg[bb] = *(const float4*)(vs + ((size_t)(b0 + bb) * 32 + o) * 16 + dq * 4);
  }

  auto stageW = [&](int i, int nb) {
    const float4* Wi = Wg + (size_t)i * 1024;
#pragma unroll
    for (int k = 0; k < 2; ++k) {
      const int p   = wv * 128 + k * 64 + lane;
      const int src = (p & ~7) | ((p & 7) ^ ((p >> 3) & 7));
      GLOAD_LDS16(Wi + src, &Wbuf[nb][(wv * 128 + k * 64) * 4]);
    }
  };
  auto stageX = [&](int sw) {
    if (t < 256) {
      const int b = t >> 4, r = t & 15;
      const int ia = i0 + sw * 8 + (r >> 1);
      GLOAD_LDS16(xg + ((size_t)(bh * 16 + b) * IC + ia) * 2 + (r & 1),
                  &xall[(wv * 64) * 4]);
    }
  };

  stageX(0);
  stageW(i0, 0);
  int cur = 0;

#pragma unroll 1
  for (int sw = 0; sw < NSW; ++sw) {
#pragma unroll 1
    for (int j = 0; j < 8; ++j) {
      const int ii = sw * 8 + j;
      __syncthreads();
      if (ii + 1 < CI) stageW(i0 + ii + 1, cur ^ 1);

      const float* Wb = &Wbuf[cur][0];
      float4 wr[8];
#pragma unroll
      for (int r = 0; r < 8; ++r)
        wr[r] = *(const float4*)&Wb[(jb + (r ^ rot)) * 4];

#pragma unroll
      for (int bb = 0; bb < 4; ++bb) {
        const int bl = bl0 + bb;
        const float4 xa = *(const float4*)&xall[bl * 64 + j * 8];
        const float4 xc = *(const float4*)&xall[bl * 64 + j * 8 + 4];
        float4 u;
        u.x = dot8(wr[0], wr[1], xa, xc);
        u.y = dot8(wr[2], wr[3], xa, xc);
        u.z = dot8(wr[4], wr[5], xa, xc);
        u.w = dot8(wr[6], wr[7], xa, xc);
        if constexpr (!WEIGHTED) {
          acc[bb].x += u.x; acc[bb].y += u.y; acc[bb].z += u.z; acc[bb].w += u.w;
        } else {
          const float4 vv = vreg[bb];
          float pd = u.x * vv.x + u.y * vv.y + u.z * vv.z + u.w * vv.w;
          pd += __shfl_xor(pd, 1);
          pd += __shfl_xor(pd, 2);
          const float p = __expf(pd);
          acc[bb].x = fmaf(p, u.x, acc[bb].x);
          acc[bb].y = fmaf(p, u.y, acc[bb].y);
          acc[bb].z = fmaf(p, u.z, acc[bb].z);
          acc[bb].w = fmaf(p, u.w, acc[bb].w);
          zacc[bb] += p;
        }
      }
      cur ^= 1;
    }
    if (sw + 1 < NSW) { __syncthreads(); stageX(sw + 1); }
  }

  float4* part4 = (float4*)part;
#pragma unroll
  for (int bb = 0; bb < 4; ++bb) {
    const int b = b0 + bb;
    part4[((size_t)ch * 64 + b) * 128 + o * 4 + dq] = acc[bb];
    if constexpr (WEIGHTED) {
      if (dq == 0) zpart[(size_t)ch * 2048 + b * 32 + o] = zacc[bb];
    }
  }
}

template<int PASS, int NCH>
__global__ __launch_bounds__(256) void reduceSquash(
    const float* __restrict__ part, const float* __restrict__ rz,
    float* __restrict__ vsio, float* __restrict__ out)
{
  const int g = blockIdx.x * 256 + threadIdx.x;
  float s = 0.f;
#pragma unroll 8
  for (int ch = 0; ch < NCH; ++ch) s += part[(size_t)ch * 32768 + g];
  if constexpr (PASS == 0) s *= (1.f / 2048.f);
  else                     s *= rz[g >> 4];

  float sq = s * s;
#pragma unroll
  for (int k = 1; k < 16; k <<= 1) sq += __shfl_xor(sq, k);
  const float f = (sq / (1.f + sq)) * rsqrtf(sq + 1e-9f);
  const float v = s * f;

  if constexpr (PASS == 0)      vsio[g] = v;
  else if constexpr (PASS == 1) vsio[g] += v;
  else                          out[g] = v;
}

template<int NCH>
__global__ __launch_bounds__(256) void zredK(
    const float* __restrict__ zpart, float* __restrict__ rz)
{
  const int j = blockIdx.x * 256 + threadIdx.x;
  float zs = 0.f;
#pragma unroll 8
  for (int ch = 0; ch < NCH; ++ch) zs += zpart[(size_t)ch * 2048 + j];
  rz[j] = 1.f / zs;
}

// ---------------------------------------------------------------------------
extern "C" void kernel_launch(void* const* d_in, const int* in_sizes, int n_in,
                              void* d_out, int out_size, void* d_ws, size_t ws_size,
                              hipStream_t stream) {
  (void)in_sizes; (void)n_in; (void)out_size;
  const float* x = (const float*)d_in[0];
  const float* W = (const float*)d_in[1];
  float* out = (float*)d_out;
  float* ws  = (float*)d_ws;

  const size_t WBF_US = (size_t)IC * 8192;
  const size_t XB_US  = (size_t)IC * 1024;

  auto runM = [&](auto tag) {
    constexpr int NCH = decltype(tag)::value;
    float* part  = ws;                                  // [NCH][32768] scrambled
    float* zpart = part + (size_t)NCH * 32768;          // [NCH][2048] scrambled
    float* vsb   = zpart + (size_t)NCH * 2048;          // [32768] scrambled vs
    unsigned short* Wbf = (unsigned short*)(vsb + 32768);
    unsigned short* xbp = Wbf + WBF_US;

    const dim3 b256(256), b512(512), gF(8 * NCH), gR(64);
    convW<<<dim3(8192), b256, 0, stream>>>(W, Wbf);
    convX<<<dim3(1024), b256, 0, stream>>>(x, xbp);
    // pass 1: uniform c -> v1
    fusedM<false, NCH><<<gF, b256, 0, stream>>>(Wbf, xbp, nullptr, part, nullptr);
    rsqM<0, NCH><<<gR, b512, 0, stream>>>(part, nullptr, vsb, nullptr);
    // pass 2: p = exp(u.v1) -> v2; vs = v1+v2
    fusedM<true, NCH><<<gF, b256, 0, stream>>>(Wbf, xbp, vsb, part, zpart);
    rsqM<1, NCH><<<gR, b512, 0, stream>>>(part, zpart, vsb, nullptr);
    // pass 3: p = exp(u.(v1+v2)) -> v3 = out
    fusedM<true, NCH><<<gF, b256, 0, stream>>>(Wbf, xbp, vsb, part, zpart);
    rsqM<2, NCH><<<gR, b512, 0, stream>>>(part, zpart, nullptr, out);
  };

  auto runF = [&](auto tag) {
    constexpr int NCH = decltype(tag)::value;
    float* part  = ws;
    float* zpart = part + (size_t)NCH * 32768;
    float* rz    = zpart + (size_t)NCH * 2048;
    float* vsb   = rz + 2048;

    const dim3 gF(4 * NCH), bF(512), b256(256), gR(128);
    fusedF32<false, NCH><<<gF, bF, 0, stream>>>(x, W, nullptr, part, nullptr);
    reduceSquash<0, NCH><<<gR, b256, 0, stream>>>(part, nullptr, vsb, nullptr);
    fusedF32<true, NCH><<<gF, bF, 0, stream>>>(x, W, vsb, part, zpart);
    zredK<NCH><<<dim3(8), b256, 0, stream>>>(zpart, rz);
    reduceSquash<1, NCH><<<gR, b256, 0, stream>>>(part, rz, vsb, nullptr);
    fusedF32<true, NCH><<<gF, bF, 0, stream>>>(x, W, vsb, part, zpart);
    zredK<NCH><<<dim3(8), b256, 0, stream>>>(zpart, rz);
    reduceSquash<2, NCH><<<gR, b256, 0, stream>>>(part, rz, nullptr, out);
  };

  auto needM = [&](size_t nch) -> size_t {
    return (nch * 32768 + nch * 2048 + 32768) * 4 + (WBF_US + XB_US) * 2;
  };
  const size_t needF256 = ((size_t)256 * 32768 + 256ul * 2048 + 2048 + 32768) * 4;

  if      (ws_size >= needM(128)) runM(std::integral_constant<int, 128>{});
  else if (ws_size >= needM(64))  runM(std::integral_constant<int, 64>{});
  else if (ws_size >= needF256)   runF(std::integral_constant<int, 256>{});
  else                            runF(std::integral_constant<int, 64>{});
}